// Round 1
// baseline (2162.357 us; speedup 1.0000x reference)
//
#include <hip/hip_runtime.h>

#define D 128
#define NN 50000
#define NS 20000

// ---------------------------------------------------------------------------
// scatter_add: out[dst[e], :] += feat[src[e], :]   (atomic, 32 thr/edge, float4)
// ---------------------------------------------------------------------------
__global__ __launch_bounds__(256) void scatter_add_k(
    const float* __restrict__ feat, const int* __restrict__ src_idx,
    const int* __restrict__ dst_idx, float* __restrict__ out, int n_edges)
{
    int tid  = blockIdx.x * blockDim.x + threadIdx.x;
    int e    = tid >> 5;
    if (e >= n_edges) return;
    int lane = tid & 31;
    int s = src_idx[e];
    int d = dst_idx[e];
    const float4 v = ((const float4*)(feat + (size_t)s * D))[lane];
    float* o = out + (size_t)d * D + lane * 4;
    atomicAdd(o + 0, v.x);
    atomicAdd(o + 1, v.y);
    atomicAdd(o + 2, v.z);
    atomicAdd(o + 3, v.w);
}

// ---------------------------------------------------------------------------
// gemm128: out[i,:] = (A[i,:] (+ A2[i,:])) @ W + bias (+ R[i,:]); optional relu
// 16 rows per block, 256 threads. W (64KB) + A tile staged in LDS.
// Thread (c=tid&31, g=tid>>5) computes rows {g, g+8} x cols [4c, 4c+4).
// ---------------------------------------------------------------------------
__global__ __launch_bounds__(256) void gemm128_k(
    const float* __restrict__ A, const float* __restrict__ A2,
    const float* __restrict__ W, const float* __restrict__ bias,
    const float* __restrict__ R, float* __restrict__ out,
    int n_rows, int relu)
{
    __shared__ float w_lds[D * D];        // 64 KB
    __shared__ float a_lds[16][D + 4];    // padded rows (528B, 16B-aligned)

    const int tid = threadIdx.x;
    const int r0  = blockIdx.x * 16;

    // stage W (flat float4 copy)
    for (int i = tid; i < D * D / 4; i += 256) {
        ((float4*)w_lds)[i] = ((const float4*)W)[i];
    }
    // stage A tile (+ optional pre-add)
    #pragma unroll
    for (int p = tid; p < 512; p += 256) {  // 512 float4 = 16x128
        int row  = p >> 5;
        int col4 = (p & 31) * 4;
        size_t gidx = (size_t)(r0 + row) * D + col4;
        float4 a = *((const float4*)(A + gidx));
        if (A2) {
            float4 b = *((const float4*)(A2 + gidx));
            a.x += b.x; a.y += b.y; a.z += b.z; a.w += b.w;
        }
        *((float4*)&a_lds[row][col4]) = a;
    }
    __syncthreads();

    const int c = tid & 31;
    const int g = tid >> 5;

    float acc0x = 0.f, acc0y = 0.f, acc0z = 0.f, acc0w = 0.f;
    float acc1x = 0.f, acc1y = 0.f, acc1z = 0.f, acc1w = 0.f;

    #pragma unroll 4
    for (int k = 0; k < D; ++k) {
        float4 b = *((const float4*)&w_lds[k * D + c * 4]);
        float a0 = a_lds[g][k];
        float a1 = a_lds[g + 8][k];
        acc0x += a0 * b.x; acc0y += a0 * b.y; acc0z += a0 * b.z; acc0w += a0 * b.w;
        acc1x += a1 * b.x; acc1y += a1 * b.y; acc1z += a1 * b.z; acc1w += a1 * b.w;
    }

    float4 bb = *((const float4*)&bias[c * 4]);

    // row g
    {
        float4 o;
        o.x = acc0x + bb.x; o.y = acc0y + bb.y; o.z = acc0z + bb.z; o.w = acc0w + bb.w;
        size_t gidx = (size_t)(r0 + g) * D + c * 4;
        if (R) {
            float4 r = *((const float4*)(R + gidx));
            o.x += r.x; o.y += r.y; o.z += r.z; o.w += r.w;
        }
        if (relu) {
            o.x = fmaxf(o.x, 0.f); o.y = fmaxf(o.y, 0.f);
            o.z = fmaxf(o.z, 0.f); o.w = fmaxf(o.w, 0.f);
        }
        *((float4*)(out + gidx)) = o;
    }
    // row g+8
    {
        float4 o;
        o.x = acc1x + bb.x; o.y = acc1y + bb.y; o.z = acc1z + bb.z; o.w = acc1w + bb.w;
        size_t gidx = (size_t)(r0 + g + 8) * D + c * 4;
        if (R) {
            float4 r = *((const float4*)(R + gidx));
            o.x += r.x; o.y += r.y; o.z += r.z; o.w += r.w;
        }
        if (relu) {
            o.x = fmaxf(o.x, 0.f); o.y = fmaxf(o.y, 0.f);
            o.z = fmaxf(o.z, 0.f); o.w = fmaxf(o.w, 0.f);
        }
        *((float4*)(out + gidx)) = o;
    }
}

// ---------------------------------------------------------------------------
extern "C" void kernel_launch(void* const* d_in, const int* in_sizes, int n_in,
                              void* d_out, int out_size, void* d_ws, size_t ws_size,
                              hipStream_t stream)
{
    const float* x     = (const float*)d_in[0];
    const float* Wm    = (const float*)d_in[1];
    const float* bm    = (const float*)d_in[2];
    const float* Wn2s0 = (const float*)d_in[3];
    const float* bn2s0 = (const float*)d_in[4];
    const float* Ws2n0 = (const float*)d_in[5];
    const float* bs2n0 = (const float*)d_in[6];
    const float* Wn2s1 = (const float*)d_in[7];
    const float* bn2s1 = (const float*)d_in[8];
    const float* Ws2n1 = (const float*)d_in[9];
    const float* bs2n1 = (const float*)d_in[10];
    const int* nei  = (const int*)d_in[11];
    const int* row0 = (const int*)d_in[12];
    const int* col0 = (const int*)d_in[13];
    const int* row1 = (const int*)d_in[14];
    const int* col1 = (const int*)d_in[15];

    const int N_E = in_sizes[11] / 2;  // 600000
    const int E_S = in_sizes[12];      // 120000

    float* out  = (float*)d_out;
    float* buf0 = (float*)d_ws;                   // NN*D scratch (agg / msg)
    float* buf1 = buf0 + (size_t)NN * D;          // NN*D (h = post-relu feats)
    float* buf2 = buf1 + (size_t)NN * D;          // NS*D (sub accumulator)
    float* buf3 = buf2 + (size_t)NS * D;          // NS*D (sub after GEMM)

    const int* src = nei;         // edge_index[0]
    const int* dst = nei + N_E;   // edge_index[1]

    const size_t nnBytes = (size_t)NN * D * sizeof(float);
    const size_t nsBytes = (size_t)NS * D * sizeof(float);

    dim3 blk(256);
    dim3 gridScatterE((N_E * 32 + 255) / 256);
    dim3 gridScatterS((E_S * 32 + 255) / 256);
    dim3 gridGemmN(NN / 16);
    dim3 gridGemmS(NS / 16);

    // ---- stage 1: agg = segment_sum(x[src], dst); h = relu((x+agg)@Wm + bm)
    hipMemsetAsync(buf0, 0, nnBytes, stream);
    scatter_add_k<<<gridScatterE, blk, 0, stream>>>(x, src, dst, buf0, N_E);
    gemm128_k<<<gridGemmN, blk, 0, stream>>>(x, buf0, Wm, bm, nullptr, buf1, NN, 1);

    // ---- level 0
    hipMemsetAsync(buf2, 0, nsBytes, stream);
    scatter_add_k<<<gridScatterS, blk, 0, stream>>>(buf1, row0, col0, buf2, E_S);
    gemm128_k<<<gridGemmS, blk, 0, stream>>>(buf2, nullptr, Wn2s0, bn2s0, nullptr, buf3, NS, 0);
    hipMemsetAsync(buf0, 0, nnBytes, stream);
    scatter_add_k<<<gridScatterS, blk, 0, stream>>>(buf3, col0, row0, buf0, E_S);
    gemm128_k<<<gridGemmN, blk, 0, stream>>>(buf0, nullptr, Ws2n0, bs2n0, buf1, out, NN, 0);

    // ---- level 1
    hipMemsetAsync(buf2, 0, nsBytes, stream);
    scatter_add_k<<<gridScatterS, blk, 0, stream>>>(out, row1, col1, buf2, E_S);
    gemm128_k<<<gridGemmS, blk, 0, stream>>>(buf2, nullptr, Wn2s1, bn2s1, nullptr, buf3, NS, 0);
    hipMemsetAsync(buf0, 0, nnBytes, stream);
    scatter_add_k<<<gridScatterS, blk, 0, stream>>>(buf3, col1, row1, buf0, E_S);
    gemm128_k<<<gridGemmN, blk, 0, stream>>>(buf0, nullptr, Ws2n1, bs2n1, out, out, NN, 0);
}

// Round 2
// 842.491 us; speedup vs baseline: 2.5666x; 2.5666x over previous
//
#include <hip/hip_runtime.h>

#define D 128
#define NN 50000
#define NS 20000

// ---------------------------------------------------------------------------
// CSR build: histogram -> exclusive scan -> cursor fill
// ---------------------------------------------------------------------------
__global__ __launch_bounds__(256) void hist_k(const int* __restrict__ seg_idx,
                                              int* __restrict__ counts, int n_edges)
{
    int e = blockIdx.x * blockDim.x + threadIdx.x;
    if (e < n_edges) atomicAdd(&counts[seg_idx[e]], 1);
}

// single-block exclusive scan: offsets[0..n], cursor[i] = offsets[i]
__global__ __launch_bounds__(1024) void scan_k(const int* __restrict__ counts,
                                               int* __restrict__ offsets,
                                               int* __restrict__ cursor, int n)
{
    __shared__ int sums[1024];
    __shared__ int carry_s;
    const int tid = threadIdx.x;
    if (tid == 0) { carry_s = 0; offsets[0] = 0; cursor[0] = 0; }
    __syncthreads();
    const int PER = 8;
    const int CHUNK = 1024 * PER;  // 8192
    for (int base = 0; base < n; base += CHUNK) {
        int vals[PER];
        int local = 0;
        int idx0 = base + tid * PER;
        #pragma unroll
        for (int i = 0; i < PER; ++i) {
            int idx = idx0 + i;
            int v = (idx < n) ? counts[idx] : 0;
            vals[i] = v;
            local += v;
        }
        sums[tid] = local;
        __syncthreads();
        // Hillis-Steele inclusive scan over the 1024 partials
        for (int off = 1; off < 1024; off <<= 1) {
            int v = (tid >= off) ? sums[tid - off] : 0;
            __syncthreads();
            sums[tid] += v;
            __syncthreads();
        }
        int carry = carry_s;
        int run = carry + (tid > 0 ? sums[tid - 1] : 0);  // exclusive prefix
        #pragma unroll
        for (int i = 0; i < PER; ++i) {
            int idx = idx0 + i;
            run += vals[i];
            if (idx < n) { offsets[idx + 1] = run; cursor[idx + 1] = run; }
        }
        __syncthreads();
        if (tid == 1023) carry_s = carry + sums[1023];
        __syncthreads();
    }
}

__global__ __launch_bounds__(256) void fill_k(const int* __restrict__ seg_idx,
                                              const int* __restrict__ val_idx,
                                              int* __restrict__ cursor,
                                              int* __restrict__ perm, int n_edges)
{
    int e = blockIdx.x * blockDim.x + threadIdx.x;
    if (e >= n_edges) return;
    int pos = atomicAdd(&cursor[seg_idx[e]], 1);
    perm[pos] = val_idx[e];
}

// ---------------------------------------------------------------------------
// gather_sum: out[s,:] = (addend ? addend[s,:] : 0) + sum_j feat[perm[j],:]
//             over j in [offsets[s], offsets[s+1]).  32 lanes per segment.
// ---------------------------------------------------------------------------
__global__ __launch_bounds__(256) void gather_sum_k(
    const float* __restrict__ feat, const int* __restrict__ offsets,
    const int* __restrict__ perm, const float* __restrict__ addend,
    float* __restrict__ out, int n_seg)
{
    int tid = blockIdx.x * 256 + threadIdx.x;
    int s = tid >> 5;
    if (s >= n_seg) return;
    int lane = tid & 31;
    int beg = offsets[s], end = offsets[s + 1];
    float4 acc = make_float4(0.f, 0.f, 0.f, 0.f);
    if (addend) acc = ((const float4*)(addend + (size_t)s * D))[lane];
    for (int j = beg; j < end; ++j) {
        int r = perm[j];
        float4 v = ((const float4*)(feat + (size_t)r * D))[lane];
        acc.x += v.x; acc.y += v.y; acc.z += v.z; acc.w += v.w;
    }
    ((float4*)(out + (size_t)s * D))[lane] = acc;
}

// ---------------------------------------------------------------------------
// gemm128: out[i,:] = A[i,:] @ W + bias (+ R[i,:]); optional relu
// 16 rows per block, 256 threads. W (64KB) + A tile staged in LDS.
// In-place safe (block reads its rows fully before writing them).
// ---------------------------------------------------------------------------
__global__ __launch_bounds__(256) void gemm128_k(
    const float* __restrict__ A, const float* __restrict__ W,
    const float* __restrict__ bias, const float* __restrict__ R,
    float* __restrict__ out, int relu)
{
    __shared__ float w_lds[D * D];        // 64 KB
    __shared__ float a_lds[16][D + 4];

    const int tid = threadIdx.x;
    const int r0  = blockIdx.x * 16;

    for (int i = tid; i < D * D / 4; i += 256) {
        ((float4*)w_lds)[i] = ((const float4*)W)[i];
    }
    #pragma unroll
    for (int p = tid; p < 512; p += 256) {  // 512 float4 = 16x128
        int row  = p >> 5;
        int col4 = (p & 31) * 4;
        size_t gidx = (size_t)(r0 + row) * D + col4;
        float4 a = *((const float4*)(A + gidx));
        *((float4*)&a_lds[row][col4]) = a;
    }
    __syncthreads();

    const int c = tid & 31;
    const int g = tid >> 5;

    float acc0x = 0.f, acc0y = 0.f, acc0z = 0.f, acc0w = 0.f;
    float acc1x = 0.f, acc1y = 0.f, acc1z = 0.f, acc1w = 0.f;

    #pragma unroll 4
    for (int k = 0; k < D; ++k) {
        float4 b = *((const float4*)&w_lds[k * D + c * 4]);
        float a0 = a_lds[g][k];
        float a1 = a_lds[g + 8][k];
        acc0x += a0 * b.x; acc0y += a0 * b.y; acc0z += a0 * b.z; acc0w += a0 * b.w;
        acc1x += a1 * b.x; acc1y += a1 * b.y; acc1z += a1 * b.z; acc1w += a1 * b.w;
    }

    float4 bb = *((const float4*)&bias[c * 4]);

    #pragma unroll
    for (int h = 0; h < 2; ++h) {
        float4 o;
        if (h == 0) { o.x = acc0x; o.y = acc0y; o.z = acc0z; o.w = acc0w; }
        else        { o.x = acc1x; o.y = acc1y; o.z = acc1z; o.w = acc1w; }
        o.x += bb.x; o.y += bb.y; o.z += bb.z; o.w += bb.w;
        size_t gidx = (size_t)(r0 + g + h * 8) * D + c * 4;
        if (R) {
            float4 r = *((const float4*)(R + gidx));
            o.x += r.x; o.y += r.y; o.z += r.z; o.w += r.w;
        }
        if (relu) {
            o.x = fmaxf(o.x, 0.f); o.y = fmaxf(o.y, 0.f);
            o.z = fmaxf(o.z, 0.f); o.w = fmaxf(o.w, 0.f);
        }
        *((float4*)(out + gidx)) = o;
    }
}

// ---------------------------------------------------------------------------
extern "C" void kernel_launch(void* const* d_in, const int* in_sizes, int n_in,
                              void* d_out, int out_size, void* d_ws, size_t ws_size,
                              hipStream_t stream)
{
    const float* x     = (const float*)d_in[0];
    const float* Wm    = (const float*)d_in[1];
    const float* bm    = (const float*)d_in[2];
    const float* Wn2s0 = (const float*)d_in[3];
    const float* bn2s0 = (const float*)d_in[4];
    const float* Ws2n0 = (const float*)d_in[5];
    const float* bs2n0 = (const float*)d_in[6];
    const float* Wn2s1 = (const float*)d_in[7];
    const float* bn2s1 = (const float*)d_in[8];
    const float* Ws2n1 = (const float*)d_in[9];
    const float* bs2n1 = (const float*)d_in[10];
    const int* nei  = (const int*)d_in[11];
    const int* row0 = (const int*)d_in[12];
    const int* col0 = (const int*)d_in[13];
    const int* row1 = (const int*)d_in[14];
    const int* col1 = (const int*)d_in[15];

    const int N_E = in_sizes[11] / 2;  // 600000
    const int E_S = in_sizes[12];      // 120000

    const int* src = nei;         // edge_index[0]
    const int* dst = nei + N_E;   // edge_index[1]

    float* out  = (float*)d_out;
    float* buf0 = (float*)d_ws;                   // NN*D
    float* buf1 = buf0 + (size_t)NN * D;          // NN*D  (h)
    float* buf2 = buf1 + (size_t)NN * D;          // NS*D  (sub, in-place GEMM)

    // int arena
    int* ip = (int*)(buf2 + (size_t)NS * D);
    // big pattern (seg=dst NN, val=src)
    int* cntB = ip;            ip += NN;
    int* offB = ip;            ip += NN + 1;
    int* curB = ip;            ip += NN + 1;
    int* prmB = ip;            ip += N_E;
    // level0 n2s (seg=col0 NS, val=row0)
    int* cnt0c = ip;           ip += NS;
    int* off0c = ip;           ip += NS + 1;
    int* cur0c = ip;           ip += NS + 1;
    int* prm0c = ip;           ip += E_S;
    // level0 s2n (seg=row0 NN, val=col0)
    int* cnt0r = ip;           ip += NN;
    int* off0r = ip;           ip += NN + 1;
    int* cur0r = ip;           ip += NN + 1;
    int* prm0r = ip;           ip += E_S;
    // level1 n2s
    int* cnt1c = ip;           ip += NS;
    int* off1c = ip;           ip += NS + 1;
    int* cur1c = ip;           ip += NS + 1;
    int* prm1c = ip;           ip += E_S;
    // level1 s2n
    int* cnt1r = ip;           ip += NN;
    int* off1r = ip;           ip += NN + 1;
    int* cur1r = ip;           ip += NN + 1;
    int* prm1r = ip;           ip += E_S;

    dim3 blk(256);
    dim3 gE((N_E + 255) / 256);
    dim3 gS((E_S + 255) / 256);
    dim3 gGatherN((NN * 32 + 255) / 256);
    dim3 gGatherS((NS * 32 + 255) / 256);
    dim3 gGemmN(NN / 16);
    dim3 gGemmS(NS / 16);

    // ---- CSR builds (5 patterns) ----
    hipMemsetAsync(cntB, 0, NN * sizeof(int), stream);
    hist_k<<<gE, blk, 0, stream>>>(dst, cntB, N_E);
    scan_k<<<1, 1024, 0, stream>>>(cntB, offB, curB, NN);
    fill_k<<<gE, blk, 0, stream>>>(dst, src, curB, prmB, N_E);

    hipMemsetAsync(cnt0c, 0, NS * sizeof(int), stream);
    hist_k<<<gS, blk, 0, stream>>>(col0, cnt0c, E_S);
    scan_k<<<1, 1024, 0, stream>>>(cnt0c, off0c, cur0c, NS);
    fill_k<<<gS, blk, 0, stream>>>(col0, row0, cur0c, prm0c, E_S);

    hipMemsetAsync(cnt0r, 0, NN * sizeof(int), stream);
    hist_k<<<gS, blk, 0, stream>>>(row0, cnt0r, E_S);
    scan_k<<<1, 1024, 0, stream>>>(cnt0r, off0r, cur0r, NN);
    fill_k<<<gS, blk, 0, stream>>>(row0, col0, cur0r, prm0r, E_S);

    hipMemsetAsync(cnt1c, 0, NS * sizeof(int), stream);
    hist_k<<<gS, blk, 0, stream>>>(col1, cnt1c, E_S);
    scan_k<<<1, 1024, 0, stream>>>(cnt1c, off1c, cur1c, NS);
    fill_k<<<gS, blk, 0, stream>>>(col1, row1, cur1c, prm1c, E_S);

    hipMemsetAsync(cnt1r, 0, NN * sizeof(int), stream);
    hist_k<<<gS, blk, 0, stream>>>(row1, cnt1r, E_S);
    scan_k<<<1, 1024, 0, stream>>>(cnt1r, off1r, cur1r, NN);
    fill_k<<<gS, blk, 0, stream>>>(row1, col1, cur1r, prm1r, E_S);

    // ---- stage 1: buf0 = x + segsum(x[src] by dst); h = relu(buf0@Wm+bm) -> buf1
    gather_sum_k<<<gGatherN, blk, 0, stream>>>(x, offB, prmB, x, buf0, NN);
    gemm128_k<<<gGemmN, blk, 0, stream>>>(buf0, Wm, bm, nullptr, buf1, 1);

    // ---- level 0
    gather_sum_k<<<gGatherS, blk, 0, stream>>>(buf1, off0c, prm0c, nullptr, buf2, NS);
    gemm128_k<<<gGemmS, blk, 0, stream>>>(buf2, Wn2s0, bn2s0, nullptr, buf2, 0);
    gather_sum_k<<<gGatherN, blk, 0, stream>>>(buf2, off0r, prm0r, nullptr, buf0, NN);
    gemm128_k<<<gGemmN, blk, 0, stream>>>(buf0, Ws2n0, bs2n0, buf1, out, 0);

    // ---- level 1
    gather_sum_k<<<gGatherS, blk, 0, stream>>>(out, off1c, prm1c, nullptr, buf2, NS);
    gemm128_k<<<gGemmS, blk, 0, stream>>>(buf2, Wn2s1, bn2s1, nullptr, buf2, 0);
    gather_sum_k<<<gGatherN, blk, 0, stream>>>(buf2, off1r, prm1r, nullptr, buf0, NN);
    gemm128_k<<<gGemmN, blk, 0, stream>>>(buf0, Ws2n1, bs2n1, out, out, 0);
}

// Round 3
// 541.383 us; speedup vs baseline: 3.9941x; 1.5562x over previous
//
#include <hip/hip_runtime.h>

#define D 128
#define NN 50000
#define NS 20000
#define L_TOT (3 * NN + 2 * NS)      // 190000 concatenated counts
#define SCAN_CHUNK 1024
#define SCAN_NBLK ((L_TOT + SCAN_CHUNK - 1) / SCAN_CHUNK)  // 186

// count-space bases: p0 dst[0,NN) | p1 col0 +NN | p2 row0 +NN+NS | p3 col1 +2NN+NS | p4 row1 +2NN+2NS

// ---------------------------------------------------------------------------
// fused 5-pattern histogram
// ---------------------------------------------------------------------------
__global__ __launch_bounds__(256) void hist5_k(
    const int* __restrict__ s0, const int* __restrict__ s1,
    const int* __restrict__ s2, const int* __restrict__ s3,
    const int* __restrict__ s4, int* __restrict__ counts, int nE, int eS)
{
    int e = blockIdx.x * 256 + threadIdx.x;
    int seg, base;
    if (e < nE) { seg = s0[e]; base = 0; }
    else {
        int r = e - nE;
        if      (r <     eS) { seg = s1[r];          base = NN; }
        else if (r < 2 * eS) { seg = s2[r - eS];     base = NN + NS; }
        else if (r < 3 * eS) { seg = s3[r - 2 * eS]; base = 2 * NN + NS; }
        else if (r < 4 * eS) { seg = s4[r - 3 * eS]; base = 2 * NN + 2 * NS; }
        else return;
    }
    atomicAdd(&counts[base + seg], 1);
}

// ---------------------------------------------------------------------------
// 3-phase scan over concatenated counts
// ---------------------------------------------------------------------------
__global__ __launch_bounds__(256) void reduce_k(const int* __restrict__ counts,
                                                int* __restrict__ blockSums, int n)
{
    __shared__ int lds[4];
    int tid = threadIdx.x;
    int base = blockIdx.x * SCAN_CHUNK;
    int s = 0;
    #pragma unroll
    for (int i = 0; i < 4; ++i) {
        int idx = base + tid + i * 256;
        if (idx < n) s += counts[idx];
    }
    #pragma unroll
    for (int off = 32; off > 0; off >>= 1) s += __shfl_down(s, off, 64);
    if ((tid & 63) == 0) lds[tid >> 6] = s;
    __syncthreads();
    if (tid == 0) blockSums[blockIdx.x] = lds[0] + lds[1] + lds[2] + lds[3];
}

__global__ __launch_bounds__(256) void scan_sums_k(int* __restrict__ blockSums, int nb)
{
    __shared__ int lds[256];
    int tid = threadIdx.x;
    lds[tid] = (tid < nb) ? blockSums[tid] : 0;
    __syncthreads();
    for (int off = 1; off < 256; off <<= 1) {
        int t = (tid >= off) ? lds[tid - off] : 0;
        __syncthreads();
        lds[tid] += t;
        __syncthreads();
    }
    if (tid < nb) blockSums[tid] = (tid > 0) ? lds[tid - 1] : 0;  // exclusive
}

__global__ __launch_bounds__(256) void scan_write_k(
    const int* __restrict__ counts, const int* __restrict__ blockSums,
    int* __restrict__ offsets, int* __restrict__ cursor, int n)
{
    __shared__ int lds[256];
    int tid = threadIdx.x;
    int base = blockIdx.x * SCAN_CHUNK + tid * 4;
    int v[4]; int s = 0;
    #pragma unroll
    for (int i = 0; i < 4; ++i) {
        int idx = base + i;
        int c = (idx < n) ? counts[idx] : 0;
        v[i] = c; s += c;
    }
    lds[tid] = s;
    __syncthreads();
    for (int off = 1; off < 256; off <<= 1) {
        int t = (tid >= off) ? lds[tid - off] : 0;
        __syncthreads();
        lds[tid] += t;
        __syncthreads();
    }
    int run = blockSums[blockIdx.x] + (tid > 0 ? lds[tid - 1] : 0);
    #pragma unroll
    for (int i = 0; i < 4; ++i) {
        int idx = base + i;
        run += v[i];
        if (idx < n) {
            offsets[idx + 1] = run;
            if (idx + 1 < n) cursor[idx + 1] = run;
        }
    }
    if (blockIdx.x == 0 && tid == 0) { offsets[0] = 0; cursor[0] = 0; }
}

// ---------------------------------------------------------------------------
// fused 5-pattern cursor fill -> global perm (absolute positions)
// ---------------------------------------------------------------------------
__global__ __launch_bounds__(256) void fill5_k(
    const int* __restrict__ s0, const int* __restrict__ v0,
    const int* __restrict__ s1, const int* __restrict__ v1,
    const int* __restrict__ s2, const int* __restrict__ v2,
    const int* __restrict__ s3, const int* __restrict__ v3,
    const int* __restrict__ s4, const int* __restrict__ v4,
    int* __restrict__ cursor, int* __restrict__ perm, int nE, int eS)
{
    int e = blockIdx.x * 256 + threadIdx.x;
    int seg, val, base;
    if (e < nE) { seg = s0[e]; val = v0[e]; base = 0; }
    else {
        int r = e - nE;
        if      (r <     eS) { seg = s1[r];          val = v1[r];          base = NN; }
        else if (r < 2 * eS) { seg = s2[r - eS];     val = v2[r - eS];     base = NN + NS; }
        else if (r < 3 * eS) { seg = s3[r - 2 * eS]; val = v3[r - 2 * eS]; base = 2 * NN + NS; }
        else if (r < 4 * eS) { seg = s4[r - 3 * eS]; val = v4[r - 3 * eS]; base = 2 * NN + 2 * NS; }
        else return;
    }
    int pos = atomicAdd(&cursor[base + seg], 1);
    perm[pos] = val;
}

// ---------------------------------------------------------------------------
// gather_sum: out[s,:] = (addend ? addend[s,:] : 0) + sum_j feat[perm[j],:]
// ---------------------------------------------------------------------------
__global__ __launch_bounds__(256) void gather_sum_k(
    const float* __restrict__ feat, const int* __restrict__ offsets,
    const int* __restrict__ perm, const float* __restrict__ addend,
    float* __restrict__ out, int n_seg)
{
    int tid = blockIdx.x * 256 + threadIdx.x;
    int s = tid >> 5;
    if (s >= n_seg) return;
    int lane = tid & 31;
    int beg = offsets[s], end = offsets[s + 1];
    float4 acc = make_float4(0.f, 0.f, 0.f, 0.f);
    if (addend) acc = ((const float4*)(addend + (size_t)s * D))[lane];
    for (int j = beg; j < end; ++j) {
        int r = perm[j];
        float4 v = ((const float4*)(feat + (size_t)r * D))[lane];
        acc.x += v.x; acc.y += v.y; acc.z += v.z; acc.w += v.w;
    }
    ((float4*)(out + (size_t)s * D))[lane] = acc;
}

// ---------------------------------------------------------------------------
// gemm128: out[i,:] = A[i,:] @ W + bias (+ R[i,:]); optional relu
// ---------------------------------------------------------------------------
__global__ __launch_bounds__(256) void gemm128_k(
    const float* __restrict__ A, const float* __restrict__ W,
    const float* __restrict__ bias, const float* __restrict__ R,
    float* __restrict__ out, int relu)
{
    __shared__ float w_lds[D * D];
    __shared__ float a_lds[16][D + 4];

    const int tid = threadIdx.x;
    const int r0  = blockIdx.x * 16;

    for (int i = tid; i < D * D / 4; i += 256) {
        ((float4*)w_lds)[i] = ((const float4*)W)[i];
    }
    #pragma unroll
    for (int p = tid; p < 512; p += 256) {
        int row  = p >> 5;
        int col4 = (p & 31) * 4;
        size_t gidx = (size_t)(r0 + row) * D + col4;
        *((float4*)&a_lds[row][col4]) = *((const float4*)(A + gidx));
    }
    __syncthreads();

    const int c = tid & 31;
    const int g = tid >> 5;

    float acc0x = 0.f, acc0y = 0.f, acc0z = 0.f, acc0w = 0.f;
    float acc1x = 0.f, acc1y = 0.f, acc1z = 0.f, acc1w = 0.f;

    #pragma unroll 4
    for (int k = 0; k < D; ++k) {
        float4 b = *((const float4*)&w_lds[k * D + c * 4]);
        float a0 = a_lds[g][k];
        float a1 = a_lds[g + 8][k];
        acc0x += a0 * b.x; acc0y += a0 * b.y; acc0z += a0 * b.z; acc0w += a0 * b.w;
        acc1x += a1 * b.x; acc1y += a1 * b.y; acc1z += a1 * b.z; acc1w += a1 * b.w;
    }

    float4 bb = *((const float4*)&bias[c * 4]);

    #pragma unroll
    for (int h = 0; h < 2; ++h) {
        float4 o;
        if (h == 0) { o.x = acc0x; o.y = acc0y; o.z = acc0z; o.w = acc0w; }
        else        { o.x = acc1x; o.y = acc1y; o.z = acc1z; o.w = acc1w; }
        o.x += bb.x; o.y += bb.y; o.z += bb.z; o.w += bb.w;
        size_t gidx = (size_t)(r0 + g + h * 8) * D + c * 4;
        if (R) {
            float4 r = *((const float4*)(R + gidx));
            o.x += r.x; o.y += r.y; o.z += r.z; o.w += r.w;
        }
        if (relu) {
            o.x = fmaxf(o.x, 0.f); o.y = fmaxf(o.y, 0.f);
            o.z = fmaxf(o.z, 0.f); o.w = fmaxf(o.w, 0.f);
        }
        *((float4*)(out + gidx)) = o;
    }
}

// ---------------------------------------------------------------------------
extern "C" void kernel_launch(void* const* d_in, const int* in_sizes, int n_in,
                              void* d_out, int out_size, void* d_ws, size_t ws_size,
                              hipStream_t stream)
{
    const float* x     = (const float*)d_in[0];
    const float* Wm    = (const float*)d_in[1];
    const float* bm    = (const float*)d_in[2];
    const float* Wn2s0 = (const float*)d_in[3];
    const float* bn2s0 = (const float*)d_in[4];
    const float* Ws2n0 = (const float*)d_in[5];
    const float* bs2n0 = (const float*)d_in[6];
    const float* Wn2s1 = (const float*)d_in[7];
    const float* bn2s1 = (const float*)d_in[8];
    const float* Ws2n1 = (const float*)d_in[9];
    const float* bs2n1 = (const float*)d_in[10];
    const int* nei  = (const int*)d_in[11];
    const int* row0 = (const int*)d_in[12];
    const int* col0 = (const int*)d_in[13];
    const int* row1 = (const int*)d_in[14];
    const int* col1 = (const int*)d_in[15];

    const int N_E = in_sizes[11] / 2;  // 600000
    const int E_S = in_sizes[12];      // 120000
    const int TOT_E = N_E + 4 * E_S;   // 1080000

    const int* src = nei;
    const int* dst = nei + N_E;

    float* out  = (float*)d_out;
    float* buf0 = (float*)d_ws;                   // NN*D
    float* buf1 = buf0 + (size_t)NN * D;          // NN*D (h)
    float* buf2 = buf1 + (size_t)NN * D;          // NS*D (in-place sub GEMM)

    int* ip      = (int*)(buf2 + (size_t)NS * D);
    int* counts  = ip;              ip += L_TOT;
    int* offsets = ip;              ip += L_TOT + 1;
    int* cursor  = ip;              ip += L_TOT;
    int* perm    = ip;              ip += TOT_E;
    int* bsums   = ip;              ip += 256;

    // per-pattern offset views (absolute positions into global perm)
    const int* offB  = offsets;                     // seg=dst  (NN)
    const int* off0c = offsets + NN;                // seg=col0 (NS)
    const int* off0r = offsets + NN + NS;           // seg=row0 (NN)
    const int* off1c = offsets + 2 * NN + NS;       // seg=col1 (NS)
    const int* off1r = offsets + 2 * NN + 2 * NS;   // seg=row1 (NN)

    dim3 blk(256);
    dim3 gTot((TOT_E + 255) / 256);
    dim3 gGatherN((NN * 32 + 255) / 256);
    dim3 gGatherS((NS * 32 + 255) / 256);
    dim3 gGemmN(NN / 16);
    dim3 gGemmS(NS / 16);

    // ---- batched CSR build (6 dispatches total) ----
    hipMemsetAsync(counts, 0, L_TOT * sizeof(int), stream);
    hist5_k<<<gTot, blk, 0, stream>>>(dst, col0, row0, col1, row1, counts, N_E, E_S);
    reduce_k<<<SCAN_NBLK, blk, 0, stream>>>(counts, bsums, L_TOT);
    scan_sums_k<<<1, blk, 0, stream>>>(bsums, SCAN_NBLK);
    scan_write_k<<<SCAN_NBLK, blk, 0, stream>>>(counts, bsums, offsets, cursor, L_TOT);
    fill5_k<<<gTot, blk, 0, stream>>>(dst, src, col0, row0, row0, col0,
                                      col1, row1, row1, col1, cursor, perm, N_E, E_S);

    // ---- stage 1: buf0 = x + segsum(x[src] by dst); buf1 = relu(buf0@Wm+bm)
    gather_sum_k<<<gGatherN, blk, 0, stream>>>(x, offB, perm, x, buf0, NN);
    gemm128_k<<<gGemmN, blk, 0, stream>>>(buf0, Wm, bm, nullptr, buf1, 1);

    // ---- level 0
    gather_sum_k<<<gGatherS, blk, 0, stream>>>(buf1, off0c, perm, nullptr, buf2, NS);
    gemm128_k<<<gGemmS, blk, 0, stream>>>(buf2, Wn2s0, bn2s0, nullptr, buf2, 0);
    gather_sum_k<<<gGatherN, blk, 0, stream>>>(buf2, off0r, perm, nullptr, buf0, NN);
    gemm128_k<<<gGemmN, blk, 0, stream>>>(buf0, Ws2n0, bs2n0, buf1, out, 0);

    // ---- level 1
    gather_sum_k<<<gGatherS, blk, 0, stream>>>(out, off1c, perm, nullptr, buf2, NS);
    gemm128_k<<<gGemmS, blk, 0, stream>>>(buf2, Wn2s1, bn2s1, nullptr, buf2, 0);
    gather_sum_k<<<gGatherN, blk, 0, stream>>>(buf2, off1r, perm, nullptr, buf0, NN);
    gemm128_k<<<gGemmN, blk, 0, stream>>>(buf0, Ws2n1, bs2n1, out, out, 0);
}

// Round 5
// 437.600 us; speedup vs baseline: 4.9414x; 1.2372x over previous
//
#include <hip/hip_runtime.h>

#define D 128
#define NN 50000
#define NS 20000
#define NNP 50048              // padded to multiple of 64 rows
#define NSP 20032
#define L_TOT (3 * NN + 2 * NS)
#define SCAN_CHUNK 1024
#define SCAN_NBLK ((L_TOT + SCAN_CHUNK - 1) / SCAN_CHUNK)
#define LDA 136                // LDS row stride in bf16 elems (272B = 17*16B, breaks bank conflicts)

typedef short s16x8 __attribute__((ext_vector_type(8)));
typedef float f32x4 __attribute__((ext_vector_type(4)));

__device__ __forceinline__ float b2f(unsigned int u) {
    u <<= 16;
    float f; __builtin_memcpy(&f, &u, 4);
    return f;
}
__device__ __forceinline__ unsigned short f2b(float f) {
    unsigned int u; __builtin_memcpy(&u, &f, 4);
    u += 0x7fffu + ((u >> 16) & 1u);       // RNE
    return (unsigned short)(u >> 16);
}

// ---------------------------------------------------------------------------
// CSR build
// ---------------------------------------------------------------------------
__global__ __launch_bounds__(256) void hist5_k(
    const int* __restrict__ s0, const int* __restrict__ s1,
    const int* __restrict__ s2, const int* __restrict__ s3,
    const int* __restrict__ s4, int* __restrict__ counts, int nE, int eS)
{
    int e = blockIdx.x * 256 + threadIdx.x;
    int seg, base;
    if (e < nE) { seg = s0[e]; base = 0; }
    else {
        int r = e - nE;
        if      (r <     eS) { seg = s1[r];          base = NN; }
        else if (r < 2 * eS) { seg = s2[r - eS];     base = NN + NS; }
        else if (r < 3 * eS) { seg = s3[r - 2 * eS]; base = 2 * NN + NS; }
        else if (r < 4 * eS) { seg = s4[r - 3 * eS]; base = 2 * NN + 2 * NS; }
        else return;
    }
    atomicAdd(&counts[base + seg], 1);
}

__global__ __launch_bounds__(256) void reduce_k(const int* __restrict__ counts,
                                                int* __restrict__ blockSums, int n)
{
    __shared__ int lds[4];
    int tid = threadIdx.x;
    int base = blockIdx.x * SCAN_CHUNK;
    int s = 0;
    #pragma unroll
    for (int i = 0; i < 4; ++i) {
        int idx = base + tid + i * 256;
        if (idx < n) s += counts[idx];
    }
    #pragma unroll
    for (int off = 32; off > 0; off >>= 1) s += __shfl_down(s, off, 64);
    if ((tid & 63) == 0) lds[tid >> 6] = s;
    __syncthreads();
    if (tid == 0) blockSums[blockIdx.x] = lds[0] + lds[1] + lds[2] + lds[3];
}

__global__ __launch_bounds__(256) void scan_sums_k(int* __restrict__ blockSums, int nb)
{
    __shared__ int lds[256];
    int tid = threadIdx.x;
    lds[tid] = (tid < nb) ? blockSums[tid] : 0;
    __syncthreads();
    for (int off = 1; off < 256; off <<= 1) {
        int t = (tid >= off) ? lds[tid - off] : 0;
        __syncthreads();
        lds[tid] += t;
        __syncthreads();
    }
    if (tid < nb) blockSums[tid] = (tid > 0) ? lds[tid - 1] : 0;
}

__global__ __launch_bounds__(256) void scan_write_k(
    const int* __restrict__ counts, const int* __restrict__ blockSums,
    int* __restrict__ offsets, int* __restrict__ cursor, int n)
{
    __shared__ int lds[256];
    int tid = threadIdx.x;
    int base = blockIdx.x * SCAN_CHUNK + tid * 4;
    int v[4]; int s = 0;
    #pragma unroll
    for (int i = 0; i < 4; ++i) {
        int idx = base + i;
        int c = (idx < n) ? counts[idx] : 0;
        v[i] = c; s += c;
    }
    lds[tid] = s;
    __syncthreads();
    for (int off = 1; off < 256; off <<= 1) {
        int t = (tid >= off) ? lds[tid - off] : 0;
        __syncthreads();
        lds[tid] += t;
        __syncthreads();
    }
    int run = blockSums[blockIdx.x] + (tid > 0 ? lds[tid - 1] : 0);
    #pragma unroll
    for (int i = 0; i < 4; ++i) {
        int idx = base + i;
        run += v[i];
        if (idx < n) {
            offsets[idx + 1] = run;
            if (idx + 1 < n) cursor[idx + 1] = run;
        }
    }
    if (blockIdx.x == 0 && tid == 0) { offsets[0] = 0; cursor[0] = 0; }
}

__global__ __launch_bounds__(256) void fill5_k(
    const int* __restrict__ s0, const int* __restrict__ v0,
    const int* __restrict__ s1, const int* __restrict__ v1,
    const int* __restrict__ s2, const int* __restrict__ v2,
    const int* __restrict__ s3, const int* __restrict__ v3,
    const int* __restrict__ s4, const int* __restrict__ v4,
    int* __restrict__ cursor, int* __restrict__ perm, int nE, int eS)
{
    int e = blockIdx.x * 256 + threadIdx.x;
    int seg, val, base;
    if (e < nE) { seg = s0[e]; val = v0[e]; base = 0; }
    else {
        int r = e - nE;
        if      (r <     eS) { seg = s1[r];          val = v1[r];          base = NN; }
        else if (r < 2 * eS) { seg = s2[r - eS];     val = v2[r - eS];     base = NN + NS; }
        else if (r < 3 * eS) { seg = s3[r - 2 * eS]; val = v3[r - 2 * eS]; base = 2 * NN + NS; }
        else if (r < 4 * eS) { seg = s4[r - 3 * eS]; val = v4[r - 3 * eS]; base = 2 * NN + 2 * NS; }
        else return;
    }
    int pos = atomicAdd(&cursor[base + seg], 1);
    perm[pos] = val;
}

// ---------------------------------------------------------------------------
// dtype converters
// ---------------------------------------------------------------------------
__global__ __launch_bounds__(256) void cvt_f2b_k(const float* __restrict__ in,
                                                 unsigned short* __restrict__ out, int n4)
{
    int i = blockIdx.x * 256 + threadIdx.x;
    if (i >= n4) return;
    float4 v = ((const float4*)in)[i];
    ushort4 o;
    o.x = f2b(v.x); o.y = f2b(v.y); o.z = f2b(v.z); o.w = f2b(v.w);
    ((ushort4*)out)[i] = o;
}

struct WPtrs { const float* w[5]; unsigned short* wt[5]; };

// wt[n*128+k] = bf16(W[k*128+n])  (transposed for B-fragment contiguity)
__global__ __launch_bounds__(256) void cvt_w_k(WPtrs p)
{
    int i = blockIdx.x * 256 + threadIdx.x;   // 5 * 16384
    int wi = i >> 14;
    int r  = i & 16383;
    int k = r >> 7, n = r & 127;
    p.wt[wi][n * 128 + k] = f2b(p.w[wi][k * 128 + n]);
}

// ---------------------------------------------------------------------------
// bf16 gather_sum: out[s,:] = (addend?addend[s,:]:0) + sum_j feat[perm[j],:]
// ---------------------------------------------------------------------------
__global__ __launch_bounds__(256) void gather_b_k(
    const unsigned short* __restrict__ feat, const int* __restrict__ offsets,
    const int* __restrict__ perm, const unsigned short* __restrict__ addend,
    unsigned short* __restrict__ out, int n_seg)
{
    int tid = blockIdx.x * 256 + threadIdx.x;
    int s = tid >> 5;
    if (s >= n_seg) return;
    int lane = tid & 31;
    int beg = offsets[s], end = offsets[s + 1];
    float a0 = 0.f, a1 = 0.f, a2 = 0.f, a3 = 0.f;
    if (addend) {
        uint2 v = ((const uint2*)(addend + (size_t)s * D))[lane];
        a0 = b2f(v.x & 0xffffu); a1 = b2f(v.x >> 16);
        a2 = b2f(v.y & 0xffffu); a3 = b2f(v.y >> 16);
    }
    for (int j = beg; j < end; ++j) {
        int r = perm[j];
        uint2 v = ((const uint2*)(feat + (size_t)r * D))[lane];
        a0 += b2f(v.x & 0xffffu); a1 += b2f(v.x >> 16);
        a2 += b2f(v.y & 0xffffu); a3 += b2f(v.y >> 16);
    }
    uint2 o;
    o.x = (unsigned int)f2b(a0) | ((unsigned int)f2b(a1) << 16);
    o.y = (unsigned int)f2b(a2) | ((unsigned int)f2b(a3) << 16);
    ((uint2*)(out + (size_t)s * D))[lane] = o;
}

// ---------------------------------------------------------------------------
// MFMA GEMM: out[i,:] = A[i,:] @ W + bias (+ R), A bf16 [M x 128], Wt bf16
// transposed [n][k]. 256 thr / 4 waves, 64 rows per block, wave w -> 16 rows.
// v_mfma_f32_16x16x32_bf16: A frag m=lane&15,k=quad*8+j; C/D col=lane&15,
// row=quad*4+reg (HW-verified layouts). 128-elem row = 16 uint4 (c in [0,16)).
// ---------------------------------------------------------------------------
__global__ __launch_bounds__(256) void gemm_mfma_k(
    const unsigned short* __restrict__ A, const unsigned short* __restrict__ Wt,
    const float* __restrict__ bias,
    const float* __restrict__ Rf, const unsigned short* __restrict__ Rb,
    float* __restrict__ outF, unsigned short* __restrict__ outB,
    int M, int relu)
{
    __shared__ unsigned short w_lds[128 * LDA];   // 34.8 KB
    __shared__ unsigned short a_lds[64 * LDA];    // 17.4 KB

    const int tid = threadIdx.x;
    const int r0  = blockIdx.x * 64;

    for (int i = tid; i < 2048; i += 256) {       // Wt: 128 rows x 16 uint4
        int row = i >> 4, c = i & 15;
        uint4 v = ((const uint4*)Wt)[i];
        *((uint4*)&w_lds[row * LDA + c * 8]) = v;
    }
    for (int i = tid; i < 1024; i += 256) {       // A: 64 rows x 16 uint4
        int row = i >> 4, c = i & 15;
        uint4 v = ((const uint4*)(A + (size_t)(r0 + row) * D))[c];
        *((uint4*)&a_lds[row * LDA + c * 8]) = v;
    }
    __syncthreads();

    const int lane = tid & 63;
    const int w    = tid >> 6;
    const int ln   = lane & 15;
    const int quad = lane >> 4;

    s16x8 af[4];
    const unsigned short* arow = &a_lds[(w * 16 + ln) * LDA + quad * 8];
    #pragma unroll
    for (int kc = 0; kc < 4; ++kc)
        af[kc] = *((const s16x8*)(arow + kc * 32));

    const int rbase = r0 + w * 16 + quad * 4;

    #pragma unroll
    for (int nt = 0; nt < 8; ++nt) {
        f32x4 acc = {0.f, 0.f, 0.f, 0.f};
        const unsigned short* brow = &w_lds[(nt * 16 + ln) * LDA + quad * 8];
        #pragma unroll
        for (int kc = 0; kc < 4; ++kc) {
            s16x8 bf = *((const s16x8*)(brow + kc * 32));
            acc = __builtin_amdgcn_mfma_f32_16x16x32_bf16(af[kc], bf, acc, 0, 0, 0);
        }
        int col = nt * 16 + ln;
        float bc = bias[col];
        #pragma unroll
        for (int r = 0; r < 4; ++r) {
            int row = rbase + r;
            if (row < M) {
                float v = acc[r] + bc;
                size_t gi = (size_t)row * D + col;
                if (Rf) v += Rf[gi];
                if (Rb) v += b2f((unsigned int)Rb[gi]);
                if (relu) v = fmaxf(v, 0.f);
                if (outF) outF[gi] = v;
                if (outB) outB[gi] = f2b(v);
            }
        }
    }
}

// ---------------------------------------------------------------------------
extern "C" void kernel_launch(void* const* d_in, const int* in_sizes, int n_in,
                              void* d_out, int out_size, void* d_ws, size_t ws_size,
                              hipStream_t stream)
{
    const float* x     = (const float*)d_in[0];
    const float* Wm    = (const float*)d_in[1];
    const float* bm    = (const float*)d_in[2];
    const float* Wn2s0 = (const float*)d_in[3];
    const float* bn2s0 = (const float*)d_in[4];
    const float* Ws2n0 = (const float*)d_in[5];
    const float* bs2n0 = (const float*)d_in[6];
    const float* Wn2s1 = (const float*)d_in[7];
    const float* bn2s1 = (const float*)d_in[8];
    const float* Ws2n1 = (const float*)d_in[9];
    const float* bs2n1 = (const float*)d_in[10];
    const int* nei  = (const int*)d_in[11];
    const int* row0 = (const int*)d_in[12];
    const int* col0 = (const int*)d_in[13];
    const int* row1 = (const int*)d_in[14];
    const int* col1 = (const int*)d_in[15];

    const int N_E = in_sizes[11] / 2;  // 600000
    const int E_S = in_sizes[12];      // 120000
    const int TOT_E = N_E + 4 * E_S;

    const int* src = nei;
    const int* dst = nei + N_E;

    float* out = (float*)d_out;

    // ---- workspace layout ----
    unsigned short* xb   = (unsigned short*)d_ws;          // x bf16 / reused as out_l0 bf16
    unsigned short* anb  = xb  + (size_t)NNP * D;          // NN-row A buffers
    unsigned short* hbf  = anb + (size_t)NNP * D;          // h bf16 (residual for gemm3)
    unsigned short* asb  = hbf + (size_t)NNP * D;          // NS-row A buffer
    unsigned short* subb = asb + (size_t)NSP * D;          // sub_x bf16
    unsigned short* wtb  = subb + (size_t)NSP * D;         // 5 transposed bf16 weights
    int* ip      = (int*)(wtb + 5 * 16384);
    int* counts  = ip;              ip += L_TOT;
    int* offsets = ip;              ip += L_TOT + 1;
    int* cursor  = ip;              ip += L_TOT;
    int* perm    = ip;              ip += TOT_E;
    int* bsums   = ip;              ip += 256;

    unsigned short* wt0 = wtb;
    unsigned short* wt1 = wtb + 16384;
    unsigned short* wt2 = wtb + 2 * 16384;
    unsigned short* wt3 = wtb + 3 * 16384;
    unsigned short* wt4 = wtb + 4 * 16384;

    const int* offB  = offsets;
    const int* off0c = offsets + NN;
    const int* off0r = offsets + NN + NS;
    const int* off1c = offsets + 2 * NN + NS;
    const int* off1r = offsets + 2 * NN + 2 * NS;

    dim3 blk(256);
    dim3 gTot((TOT_E + 255) / 256);
    dim3 gGatherN((NN * 32 + 255) / 256);
    dim3 gGatherS((NS * 32 + 255) / 256);
    dim3 gGemmN(NNP / 64);
    dim3 gGemmS(NSP / 64);
    dim3 gCvtX((NN * D / 4 + 255) / 256);
    dim3 gCvtW(5 * 16384 / 256);

    // ---- converters ----
    cvt_f2b_k<<<gCvtX, blk, 0, stream>>>(x, xb, NN * D / 4);
    WPtrs wp;
    wp.w[0] = Wm;  wp.w[1] = Wn2s0; wp.w[2] = Ws2n0; wp.w[3] = Wn2s1; wp.w[4] = Ws2n1;
    wp.wt[0] = wt0; wp.wt[1] = wt1; wp.wt[2] = wt2; wp.wt[3] = wt3; wp.wt[4] = wt4;
    cvt_w_k<<<gCvtW, blk, 0, stream>>>(wp);

    // ---- batched CSR build ----
    hipMemsetAsync(counts, 0, L_TOT * sizeof(int), stream);
    hist5_k<<<gTot, blk, 0, stream>>>(dst, col0, row0, col1, row1, counts, N_E, E_S);
    reduce_k<<<SCAN_NBLK, blk, 0, stream>>>(counts, bsums, L_TOT);
    scan_sums_k<<<1, blk, 0, stream>>>(bsums, SCAN_NBLK);
    scan_write_k<<<SCAN_NBLK, blk, 0, stream>>>(counts, bsums, offsets, cursor, L_TOT);
    fill5_k<<<gTot, blk, 0, stream>>>(dst, src, col0, row0, row0, col0,
                                      col1, row1, row1, col1, cursor, perm, N_E, E_S);

    // ---- stage 1 ----
    gather_b_k<<<gGatherN, blk, 0, stream>>>(xb, offB, perm, xb, anb, NN);
    gemm_mfma_k<<<gGemmN, blk, 0, stream>>>(anb, wt0, bm, nullptr, nullptr,
                                            nullptr, hbf, NN, 1);

    // ---- level 0 ----
    gather_b_k<<<gGatherS, blk, 0, stream>>>(hbf, off0c, perm, nullptr, asb, NS);
    gemm_mfma_k<<<gGemmS, blk, 0, stream>>>(asb, wt1, bn2s0, nullptr, nullptr,
                                            nullptr, subb, NS, 0);
    gather_b_k<<<gGatherN, blk, 0, stream>>>(subb, off0r, perm, nullptr, anb, NN);
    gemm_mfma_k<<<gGemmN, blk, 0, stream>>>(anb, wt2, bs2n0, nullptr, hbf,
                                            out, xb /*out_l0 bf16*/, NN, 0);

    // ---- level 1 ----
    gather_b_k<<<gGatherS, blk, 0, stream>>>(xb, off1c, perm, nullptr, asb, NS);
    gemm_mfma_k<<<gGemmS, blk, 0, stream>>>(asb, wt3, bn2s1, nullptr, nullptr,
                                            nullptr, subb, NS, 0);
    gather_b_k<<<gGatherN, blk, 0, stream>>>(subb, off1r, perm, nullptr, anb, NN);
    gemm_mfma_k<<<gGemmN, blk, 0, stream>>>(anb, wt4, bs2n1, out, nullptr,
                                            out, nullptr, NN, 0);
}

// Round 6
// 392.828 us; speedup vs baseline: 5.5046x; 1.1140x over previous
//
#include <hip/hip_runtime.h>

#define D 128
#define NN 50000
#define NS 20000
#define NNP 50048              // padded to multiple of 64 rows
#define NSP 20032
#define L_TOT (3 * NN + 2 * NS)
#define SCAN_CHUNK 1024
#define SCAN_NBLK ((L_TOT + SCAN_CHUNK - 1) / SCAN_CHUNK)
#define LDA 136                // LDS row stride in bf16 elems (breaks bank conflicts)

typedef short s16x8 __attribute__((ext_vector_type(8)));
typedef float f32x4 __attribute__((ext_vector_type(4)));

__device__ __forceinline__ float b2f(unsigned int u) {
    u <<= 16;
    float f; __builtin_memcpy(&f, &u, 4);
    return f;
}
__device__ __forceinline__ unsigned short f2b(float f) {
    unsigned int u; __builtin_memcpy(&u, &f, 4);
    u += 0x7fffu + ((u >> 16) & 1u);       // RNE
    return (unsigned short)(u >> 16);
}
__device__ __forceinline__ void acc8(float* a, uint4 v) {
    a[0] += b2f(v.x & 0xffffu); a[1] += b2f(v.x >> 16);
    a[2] += b2f(v.y & 0xffffu); a[3] += b2f(v.y >> 16);
    a[4] += b2f(v.z & 0xffffu); a[5] += b2f(v.z >> 16);
    a[6] += b2f(v.w & 0xffffu); a[7] += b2f(v.w >> 16);
}

// ---------------------------------------------------------------------------
// prep: convert x -> bf16, transpose+convert 5 weights, zero counts (1 launch)
// ---------------------------------------------------------------------------
struct PrepArgs {
    const float* x; unsigned short* xb;
    const float* w[5]; unsigned short* wt[5];
    int* counts;
};
#define NX4 (NN * D / 4)                  // 1,600,000 float4 -> ushort4
#define NW  (5 * 16384)                   // 81,920 scalar transposed elems
#define NC4 (L_TOT / 4)                   // 47,500 int4 zeros
__global__ __launch_bounds__(256) void prep_k(PrepArgs p)
{
    int i = blockIdx.x * 256 + threadIdx.x;
    if (i < NX4) {
        float4 v = ((const float4*)p.x)[i];
        ushort4 o;
        o.x = f2b(v.x); o.y = f2b(v.y); o.z = f2b(v.z); o.w = f2b(v.w);
        ((ushort4*)p.xb)[i] = o;
        return;
    }
    i -= NX4;
    if (i < NW) {
        int wi = i >> 14;
        int r  = i & 16383;
        int k = r >> 7, n = r & 127;
        p.wt[wi][n * 128 + k] = f2b(p.w[wi][k * 128 + n]);
        return;
    }
    i -= NW;
    if (i < NC4) {
        int4 z = {0, 0, 0, 0};
        ((int4*)p.counts)[i] = z;
    }
}

// ---------------------------------------------------------------------------
// CSR build
// ---------------------------------------------------------------------------
__global__ __launch_bounds__(256) void hist5_k(
    const int* __restrict__ s0, const int* __restrict__ s1,
    const int* __restrict__ s2, const int* __restrict__ s3,
    const int* __restrict__ s4, int* __restrict__ counts, int nE, int eS)
{
    int e = blockIdx.x * 256 + threadIdx.x;
    int seg, base;
    if (e < nE) { seg = s0[e]; base = 0; }
    else {
        int r = e - nE;
        if      (r <     eS) { seg = s1[r];          base = NN; }
        else if (r < 2 * eS) { seg = s2[r - eS];     base = NN + NS; }
        else if (r < 3 * eS) { seg = s3[r - 2 * eS]; base = 2 * NN + NS; }
        else if (r < 4 * eS) { seg = s4[r - 3 * eS]; base = 2 * NN + 2 * NS; }
        else return;
    }
    atomicAdd(&counts[base + seg], 1);
}

__global__ __launch_bounds__(256) void reduce_k(const int* __restrict__ counts,
                                                int* __restrict__ blockSums, int n)
{
    __shared__ int lds[4];
    int tid = threadIdx.x;
    int base = blockIdx.x * SCAN_CHUNK;
    int s = 0;
    #pragma unroll
    for (int i = 0; i < 4; ++i) {
        int idx = base + tid + i * 256;
        if (idx < n) s += counts[idx];
    }
    #pragma unroll
    for (int off = 32; off > 0; off >>= 1) s += __shfl_down(s, off, 64);
    if ((tid & 63) == 0) lds[tid >> 6] = s;
    __syncthreads();
    if (tid == 0) blockSums[blockIdx.x] = lds[0] + lds[1] + lds[2] + lds[3];
}

__global__ __launch_bounds__(256) void scan_sums_k(int* __restrict__ blockSums, int nb)
{
    __shared__ int lds[256];
    int tid = threadIdx.x;
    lds[tid] = (tid < nb) ? blockSums[tid] : 0;
    __syncthreads();
    for (int off = 1; off < 256; off <<= 1) {
        int t = (tid >= off) ? lds[tid - off] : 0;
        __syncthreads();
        lds[tid] += t;
        __syncthreads();
    }
    if (tid < nb) blockSums[tid] = (tid > 0) ? lds[tid - 1] : 0;
}

__global__ __launch_bounds__(256) void scan_write_k(
    const int* __restrict__ counts, const int* __restrict__ blockSums,
    int* __restrict__ offsets, int* __restrict__ cursor, int n)
{
    __shared__ int lds[256];
    int tid = threadIdx.x;
    int base = blockIdx.x * SCAN_CHUNK + tid * 4;
    int v[4]; int s = 0;
    #pragma unroll
    for (int i = 0; i < 4; ++i) {
        int idx = base + i;
        int c = (idx < n) ? counts[idx] : 0;
        v[i] = c; s += c;
    }
    lds[tid] = s;
    __syncthreads();
    for (int off = 1; off < 256; off <<= 1) {
        int t = (tid >= off) ? lds[tid - off] : 0;
        __syncthreads();
        lds[tid] += t;
        __syncthreads();
    }
    int run = blockSums[blockIdx.x] + (tid > 0 ? lds[tid - 1] : 0);
    #pragma unroll
    for (int i = 0; i < 4; ++i) {
        int idx = base + i;
        run += v[i];
        if (idx < n) {
            offsets[idx + 1] = run;
            if (idx + 1 < n) cursor[idx + 1] = run;
        }
    }
    if (blockIdx.x == 0 && tid == 0) { offsets[0] = 0; cursor[0] = 0; }
}

__global__ __launch_bounds__(256) void fill5_k(
    const int* __restrict__ s0, const int* __restrict__ v0,
    const int* __restrict__ s1, const int* __restrict__ v1,
    const int* __restrict__ s2, const int* __restrict__ v2,
    const int* __restrict__ s3, const int* __restrict__ v3,
    const int* __restrict__ s4, const int* __restrict__ v4,
    int* __restrict__ cursor, int* __restrict__ perm, int nE, int eS)
{
    int e = blockIdx.x * 256 + threadIdx.x;
    int seg, val, base;
    if (e < nE) { seg = s0[e]; val = v0[e]; base = 0; }
    else {
        int r = e - nE;
        if      (r <     eS) { seg = s1[r];          val = v1[r];          base = NN; }
        else if (r < 2 * eS) { seg = s2[r - eS];     val = v2[r - eS];     base = NN + NS; }
        else if (r < 3 * eS) { seg = s3[r - 2 * eS]; val = v3[r - 2 * eS]; base = 2 * NN + NS; }
        else if (r < 4 * eS) { seg = s4[r - 3 * eS]; val = v4[r - 3 * eS]; base = 2 * NN + 2 * NS; }
        else return;
    }
    int pos = atomicAdd(&cursor[base + seg], 1);
    perm[pos] = val;
}

// ---------------------------------------------------------------------------
// bf16 gather_sum: 16 lanes/segment, uint4 (16B) loads, 4-edge unroll.
// out[s,:] = (addend?addend[s,:]:0) + sum_j feat[perm[j],:]
// ---------------------------------------------------------------------------
__global__ __launch_bounds__(256) void gather_b_k(
    const unsigned short* __restrict__ feat, const int* __restrict__ offsets,
    const int* __restrict__ perm, const unsigned short* __restrict__ addend,
    unsigned short* __restrict__ out, int n_seg)
{
    int tid = blockIdx.x * 256 + threadIdx.x;
    int s = tid >> 4;
    if (s >= n_seg) return;
    int lane = tid & 15;
    const uint4* f4 = (const uint4*)feat;        // one row = 16 uint4
    int beg = offsets[s], end = offsets[s + 1];
    float a[8] = {0.f, 0.f, 0.f, 0.f, 0.f, 0.f, 0.f, 0.f};
    float b[8] = {0.f, 0.f, 0.f, 0.f, 0.f, 0.f, 0.f, 0.f};
    if (addend) {
        uint4 v = ((const uint4*)(addend + (size_t)s * D))[lane];
        acc8(a, v);
    }
    int j = beg;
    for (; j + 3 < end; j += 4) {
        int r0 = perm[j], r1 = perm[j + 1], r2 = perm[j + 2], r3 = perm[j + 3];
        uint4 v0 = f4[(size_t)r0 * 16 + lane];
        uint4 v1 = f4[(size_t)r1 * 16 + lane];
        uint4 v2 = f4[(size_t)r2 * 16 + lane];
        uint4 v3 = f4[(size_t)r3 * 16 + lane];
        acc8(a, v0); acc8(b, v1); acc8(a, v2); acc8(b, v3);
    }
    for (; j < end; ++j) {
        uint4 v = f4[(size_t)perm[j] * 16 + lane];
        acc8(a, v);
    }
    #pragma unroll
    for (int i = 0; i < 8; ++i) a[i] += b[i];
    uint4 o;
    o.x = (unsigned int)f2b(a[0]) | ((unsigned int)f2b(a[1]) << 16);
    o.y = (unsigned int)f2b(a[2]) | ((unsigned int)f2b(a[3]) << 16);
    o.z = (unsigned int)f2b(a[4]) | ((unsigned int)f2b(a[5]) << 16);
    o.w = (unsigned int)f2b(a[6]) | ((unsigned int)f2b(a[7]) << 16);
    ((uint4*)(out + (size_t)s * D))[lane] = o;
}

// ---------------------------------------------------------------------------
// MFMA GEMM: out[i,:] = A[i,:] @ W + bias (+ R), A bf16 [M x 128], Wt bf16
// transposed [n][k]. 256 thr / 4 waves, 64 rows per block, wave w -> 16 rows.
// ---------------------------------------------------------------------------
__global__ __launch_bounds__(256) void gemm_mfma_k(
    const unsigned short* __restrict__ A, const unsigned short* __restrict__ Wt,
    const float* __restrict__ bias,
    const float* __restrict__ Rf, const unsigned short* __restrict__ Rb,
    float* __restrict__ outF, unsigned short* __restrict__ outB,
    int M, int relu)
{
    __shared__ unsigned short w_lds[128 * LDA];
    __shared__ unsigned short a_lds[64 * LDA];

    const int tid = threadIdx.x;
    const int r0  = blockIdx.x * 64;

    for (int i = tid; i < 2048; i += 256) {       // Wt: 128 rows x 16 uint4
        int row = i >> 4, c = i & 15;
        uint4 v = ((const uint4*)Wt)[i];
        *((uint4*)&w_lds[row * LDA + c * 8]) = v;
    }
    for (int i = tid; i < 1024; i += 256) {       // A: 64 rows x 16 uint4
        int row = i >> 4, c = i & 15;
        uint4 v = ((const uint4*)(A + (size_t)(r0 + row) * D))[c];
        *((uint4*)&a_lds[row * LDA + c * 8]) = v;
    }
    __syncthreads();

    const int lane = tid & 63;
    const int w    = tid >> 6;
    const int ln   = lane & 15;
    const int quad = lane >> 4;

    s16x8 af[4];
    const unsigned short* arow = &a_lds[(w * 16 + ln) * LDA + quad * 8];
    #pragma unroll
    for (int kc = 0; kc < 4; ++kc)
        af[kc] = *((const s16x8*)(arow + kc * 32));

    const int rbase = r0 + w * 16 + quad * 4;

    #pragma unroll
    for (int nt = 0; nt < 8; ++nt) {
        f32x4 acc = {0.f, 0.f, 0.f, 0.f};
        const unsigned short* brow = &w_lds[(nt * 16 + ln) * LDA + quad * 8];
        #pragma unroll
        for (int kc = 0; kc < 4; ++kc) {
            s16x8 bf = *((const s16x8*)(brow + kc * 32));
            acc = __builtin_amdgcn_mfma_f32_16x16x32_bf16(af[kc], bf, acc, 0, 0, 0);
        }
        int col = nt * 16 + ln;
        float bc = bias[col];
        #pragma unroll
        for (int r = 0; r < 4; ++r) {
            int row = rbase + r;
            if (row < M) {
                float v = acc[r] + bc;
                size_t gi = (size_t)row * D + col;
                if (Rf) v += Rf[gi];
                if (Rb) v += b2f((unsigned int)Rb[gi]);
                if (relu) v = fmaxf(v, 0.f);
                if (outF) outF[gi] = v;
                if (outB) outB[gi] = f2b(v);
            }
        }
    }
}

// ---------------------------------------------------------------------------
extern "C" void kernel_launch(void* const* d_in, const int* in_sizes, int n_in,
                              void* d_out, int out_size, void* d_ws, size_t ws_size,
                              hipStream_t stream)
{
    const float* x     = (const float*)d_in[0];
    const float* Wm    = (const float*)d_in[1];
    const float* bm    = (const float*)d_in[2];
    const float* Wn2s0 = (const float*)d_in[3];
    const float* bn2s0 = (const float*)d_in[4];
    const float* Ws2n0 = (const float*)d_in[5];
    const float* bs2n0 = (const float*)d_in[6];
    const float* Wn2s1 = (const float*)d_in[7];
    const float* bn2s1 = (const float*)d_in[8];
    const float* Ws2n1 = (const float*)d_in[9];
    const float* bs2n1 = (const float*)d_in[10];
    const int* nei  = (const int*)d_in[11];
    const int* row0 = (const int*)d_in[12];
    const int* col0 = (const int*)d_in[13];
    const int* row1 = (const int*)d_in[14];
    const int* col1 = (const int*)d_in[15];

    const int N_E = in_sizes[11] / 2;  // 600000
    const int E_S = in_sizes[12];      // 120000
    const int TOT_E = N_E + 4 * E_S;

    const int* src = nei;
    const int* dst = nei + N_E;

    float* out = (float*)d_out;

    // ---- workspace layout ----
    unsigned short* xb   = (unsigned short*)d_ws;          // x bf16 / out_l0 bf16
    unsigned short* anb  = xb  + (size_t)NNP * D;
    unsigned short* hbf  = anb + (size_t)NNP * D;
    unsigned short* asb  = hbf + (size_t)NNP * D;
    unsigned short* subb = asb + (size_t)NSP * D;
    unsigned short* wtb  = subb + (size_t)NSP * D;
    int* ip      = (int*)(wtb + 5 * 16384);
    int* counts  = ip;              ip += L_TOT;
    int* offsets = ip;              ip += L_TOT + 1;
    int* cursor  = ip;              ip += L_TOT;
    int* perm    = ip;              ip += TOT_E;
    int* bsums   = ip;              ip += 256;

    unsigned short* wt0 = wtb;
    unsigned short* wt1 = wtb + 16384;
    unsigned short* wt2 = wtb + 2 * 16384;
    unsigned short* wt3 = wtb + 3 * 16384;
    unsigned short* wt4 = wtb + 4 * 16384;

    const int* offB  = offsets;
    const int* off0c = offsets + NN;
    const int* off0r = offsets + NN + NS;
    const int* off1c = offsets + 2 * NN + NS;
    const int* off1r = offsets + 2 * NN + 2 * NS;

    dim3 blk(256);
    dim3 gTot((TOT_E + 255) / 256);
    dim3 gGatherN((NN * 16 + 255) / 256);
    dim3 gGatherS((NS * 16 + 255) / 256);
    dim3 gGemmN(NNP / 64);
    dim3 gGemmS(NSP / 64);
    dim3 gPrep((NX4 + NW + NC4 + 255) / 256);

    // ---- prep: x->bf16, W->Wt bf16, zero counts (one launch) ----
    PrepArgs pa;
    pa.x = x; pa.xb = xb;
    pa.w[0] = Wm;  pa.w[1] = Wn2s0; pa.w[2] = Ws2n0; pa.w[3] = Wn2s1; pa.w[4] = Ws2n1;
    pa.wt[0] = wt0; pa.wt[1] = wt1; pa.wt[2] = wt2; pa.wt[3] = wt3; pa.wt[4] = wt4;
    pa.counts = counts;
    prep_k<<<gPrep, blk, 0, stream>>>(pa);

    // ---- batched CSR build ----
    hist5_k<<<gTot, blk, 0, stream>>>(dst, col0, row0, col1, row1, counts, N_E, E_S);
    reduce_k<<<SCAN_NBLK, blk, 0, stream>>>(counts, bsums, L_TOT);
    scan_sums_k<<<1, blk, 0, stream>>>(bsums, SCAN_NBLK);
    scan_write_k<<<SCAN_NBLK, blk, 0, stream>>>(counts, bsums, offsets, cursor, L_TOT);
    fill5_k<<<gTot, blk, 0, stream>>>(dst, src, col0, row0, row0, col0,
                                      col1, row1, row1, col1, cursor, perm, N_E, E_S);

    // ---- stage 1 ----
    gather_b_k<<<gGatherN, blk, 0, stream>>>(xb, offB, perm, xb, anb, NN);
    gemm_mfma_k<<<gGemmN, blk, 0, stream>>>(anb, wt0, bm, nullptr, nullptr,
                                            nullptr, hbf, NN, 1);

    // ---- level 0 ----
    gather_b_k<<<gGatherS, blk, 0, stream>>>(hbf, off0c, perm, nullptr, asb, NS);
    gemm_mfma_k<<<gGemmS, blk, 0, stream>>>(asb, wt1, bn2s0, nullptr, nullptr,
                                            nullptr, subb, NS, 0);
    gather_b_k<<<gGatherN, blk, 0, stream>>>(subb, off0r, perm, nullptr, anb, NN);
    gemm_mfma_k<<<gGemmN, blk, 0, stream>>>(anb, wt2, bs2n0, nullptr, hbf,
                                            out, xb /*out_l0 bf16*/, NN, 0);

    // ---- level 1 ----
    gather_b_k<<<gGatherS, blk, 0, stream>>>(xb, off1c, perm, nullptr, asb, NS);
    gemm_mfma_k<<<gGemmS, blk, 0, stream>>>(asb, wt3, bn2s1, nullptr, nullptr,
                                            nullptr, subb, NS, 0);
    gather_b_k<<<gGatherN, blk, 0, stream>>>(subb, off1r, perm, nullptr, anb, NN);
    gemm_mfma_k<<<gGemmN, blk, 0, stream>>>(anb, wt4, bs2n1, out, nullptr,
                                            out, nullptr, NN, 0);
}